// Round 1
// baseline (3704.909 us; speedup 1.0000x reference)
//
#include <hip/hip_runtime.h>
#include <hip/hip_bf16.h>
#include <cstddef>
#include <cstdint>

// Problem constants
#define NB 32          // batch
#define NS 512         // seq len
#define ND 512         // d_model == hid
#define NG 2048        // 4*hid gate cols per layer

// ws layout (bytes).  Poison-mailbox protocol: NO flags on the forward path.
//   flags[64] : layer-1 progress (anti-overwrite backpressure, checked every 4 steps)
//   h0 : 8 slots x 32768 B frag-order bf16, slot = t & 7
//   h1 : 4 slots x 32768 B,                 slot = t & 3
// All h slots init to 0xFF (poison).  Producers publish packed 32-bit words
// (2 x bf16; legit h in (-1,1) can never encode 0xFFFF).  Consumers poll the
// data words directly until != 0xFFFFFFFF -- the successful poll's loads ARE
// the MFMA fragments (one roundtrip, no flag hop, no release fence).
// A producer re-poisons its region of slot (t+2)&mask at step t (that slot
// holds h[t-6] / h[t-2]); the mid-barrier's implicit vmcnt(0) drain orders the
// poison before this step's publish, and every consumer's poll is transitively
// ordered behind a later publish it already consumed -> no stale-read races.
#define FLAGS_OFF 0
#define H0_OFF    4096
#define H1_OFF    (H0_OFF + 8 * 32768)
#define CTRL_BYTES (H1_OFF + 4 * 32768)     // 397312 bytes total ws use

#define POISON   0xFFFFFFFFu
#define SPIN_LIM 16384                      // fail-safe: never hang

typedef __attribute__((ext_vector_type(8))) short short8;
typedef __attribute__((ext_vector_type(8))) __bf16 bf16x8;
typedef __attribute__((ext_vector_type(4))) float f32x4;

static __device__ __forceinline__ unsigned short f2bf(float f) {
  __hip_bfloat16 h = __float2bfloat16(f);
  return __builtin_bit_cast(unsigned short, h);
}

static __device__ __forceinline__ short8 pack8(float4 a, float4 b) {
  short8 r;
  r[0] = (short)f2bf(a.x); r[1] = (short)f2bf(a.y);
  r[2] = (short)f2bf(a.z); r[3] = (short)f2bf(a.w);
  r[4] = (short)f2bf(b.x); r[5] = (short)f2bf(b.y);
  r[6] = (short)f2bf(b.z); r[7] = (short)f2bf(b.w);
  return r;
}

static __device__ __forceinline__ unsigned long long aload64(const unsigned char* p) {
  return __hip_atomic_load(reinterpret_cast<const unsigned long long*>(p),
                           __ATOMIC_RELAXED, __HIP_MEMORY_SCOPE_AGENT);
}

// ---------------- Kernel 1: fp32 embedding gather (output 1 + LSTM x) -------
__global__ __launch_bounds__(256) void gather_f32(const int* __restrict__ src,
                                                  const float* __restrict__ emb,
                                                  float* __restrict__ out1) {
  int tid = blockIdx.x * 256 + threadIdx.x;   // 0 .. 2097151 (float4 granules)
  int bt = tid >> 7;                          // b*512 + t
  int k4 = (tid & 127) << 2;
  int s  = src[bt];
  float4 v = *reinterpret_cast<const float4*>(emb + (size_t)s * ND + k4);
  *reinterpret_cast<float4*>(out1 + (size_t)bt * ND + k4) = v;
}

// ---------------- Kernel 2: persistent 2-layer LSTM ----------------
// grid = 128 blocks: L = bid>>6, slice = bid&63 (8 hidden units / 32 gate cols)
__global__ __launch_bounds__(256, 1) void lstm_persist(
    const float* __restrict__ Wk, const float* __restrict__ Wr,
    const float* __restrict__ bias_g,
    const float* __restrict__ x_f32,          // gathered fp32 emb (out1)
    unsigned char* ws, float* __restrict__ out0) {

  __shared__ __attribute__((aligned(16))) char smem[66048];

  const int tid   = threadIdx.x;
  const int bid   = blockIdx.x;
  const int L     = bid >> 6;
  const int slice = bid & 63;
  const int u0    = slice * 8;
  const int lane  = tid & 63;
  const int wv    = tid >> 6;
  const int m     = wv & 1;    // batch mtile (16 rows)
  const int kh    = wv >> 1;   // K half (16 ktiles of 32)

  const float* WkL = Wk + (size_t)L * 512 * NG;
  const float* WrL = Wr + (size_t)L * 512 * NG;

  // ---- phase 1: stage transposed weight slice into LDS: WT[32 cols][1032 k]
  short* WT = reinterpret_cast<short*>(smem);
  for (int idx = tid; idx < 1024 * 32; idx += 256) {
    int k = idx >> 5, c = idx & 31;
    int gc = (c >> 3) * 512 + u0 + (c & 7);        // cols ordered [i8|f8|g8|o8]
    float v = (k < 512) ? WkL[(size_t)k * NG + gc]
                        : WrL[(size_t)(k - 512) * NG + gc];
    WT[c * 1032 + k] = (short)f2bf(v);
  }
  __syncthreads();

  // ---- preload static B fragments into VGPRs (32 frags = 128 VGPRs/thread)
  short8 Bf[2][16];
  {
    int colr = lane & 15;
    int q    = lane >> 4;
#pragma unroll
    for (int n = 0; n < 2; ++n)
#pragma unroll
      for (int kt2 = 0; kt2 < 16; ++kt2) {
        int k = (kh * 16 + kt2) * 32 + q * 8;
        Bf[n][kt2] = *reinterpret_cast<const short8*>(WT + (n * 16 + colr) * 1032 + k);
      }
  }
  __syncthreads();

  // ---- LDS reused: z partials [2 kh][32 b][33] f32 + bias[32]
  float* zbuf = reinterpret_cast<float*>(smem);   // 2112 floats
  float* blds = zbuf + 2112;                      // 32 floats
  if (tid < 32) {
    int gc = (tid >> 3) * 512 + u0 + (tid & 7);
    blds[tid] = bias_g[L * NG + gc];
  }
  __syncthreads();

  int* flags = reinterpret_cast<int*>(ws + FLAGS_OFF);
  unsigned char* h0buf = ws + H0_OFF;
  unsigned char* h1buf = ws + H1_OFF;

  // epilogue thread mapping: (b,u) and publish offset into frag-order h buffer
  const int eb = tid >> 3, eu = tid & 7;
  const int pub_off = ((u0 >> 5) * 2 + (eb >> 4)) * 1024 +
                      ((u0 & 31) >> 3) * 256 + (eb & 15) * 16 + eu * 2;

  float creg = 0.f;

  for (int t = 0; t < NS; ++t) {
    short8 af[16];

    // layer0 backpressure flag load: ISSUED before the data poll so its
    // latency is hidden; only CHECKED afterwards. Gates poison/overwrite of
    // h0 slots that layer1 may still be reading (need l1prog >= t-2, every 4).
    int bpf = 0;
    const bool bp = (L == 0) && ((t & 3) == 0);
    if (bp) bpf = (int)__hip_atomic_load(flags + lane, __ATOMIC_RELAXED,
                                         __HIP_MEMORY_SCOPE_AGENT);

    if (L == 0 && kh == 0) {
      // x side: no dependency, fully off the critical path (fp32 + pack)
      int bb = m * 16 + (lane & 15);
      const float* xr = x_f32 + ((size_t)bb * NS + t) * ND + (lane >> 4) * 8;
#pragma unroll
      for (int kt2 = 0; kt2 < 16; ++kt2) {
        float4 v0 = *reinterpret_cast<const float4*>(xr + kt2 * 32);
        float4 v1 = *reinterpret_cast<const float4*>(xr + kt2 * 32 + 4);
        af[kt2] = pack8(v0, v1);
      }
    } else if (t == 0 && (L == 0 || kh == 1)) {
      // self-layer h[-1] == 0 (skip the slot entirely; slots start poisoned)
      const short8 zz = {0, 0, 0, 0, 0, 0, 0, 0};
#pragma unroll
      for (int kt2 = 0; kt2 < 16; ++kt2) af[kt2] = zz;
    } else {
      const unsigned char* hb;
      if (L == 0)       hb = h0buf + (size_t)((t - 1) & 7) * 32768;  // h0[t-1]
      else if (kh == 0) hb = h0buf + (size_t)(t & 7) * 32768;        // h0[t]
      else              hb = h1buf + (size_t)((t - 1) & 3) * 32768;  // h1[t-1]
      const unsigned char* ha = hb + (size_t)m * 1024 + lane * 16;
      // data poll: batched 32x8B agent-scope loads into af, then check; the
      // successful round's loads ARE the MFMA A-fragments (one roundtrip).
      int spin = 0;
      for (;;) {
#pragma unroll
        for (int kt2 = 0; kt2 < 16; ++kt2) {
          unsigned long long* ap = reinterpret_cast<unsigned long long*>(&af[kt2]);
          ap[0] = aload64(ha + (size_t)kt2 * 2048);
          ap[1] = aload64(ha + (size_t)kt2 * 2048 + 8);
        }
        unsigned ok = 1u;
#pragma unroll
        for (int kt2 = 0; kt2 < 16; ++kt2) {
          const unsigned long long* ap =
              reinterpret_cast<const unsigned long long*>(&af[kt2]);
          unsigned w0 = (unsigned)ap[0], w1 = (unsigned)(ap[0] >> 32);
          unsigned w2 = (unsigned)ap[1], w3 = (unsigned)(ap[1] >> 32);
          ok &= (unsigned)(w0 != POISON) & (unsigned)(w1 != POISON) &
                (unsigned)(w2 != POISON) & (unsigned)(w3 != POISON);
        }
        if (ok || ++spin > SPIN_LIM) break;   // bail-out: no hang, ever
        __builtin_amdgcn_s_sleep(1);
      }
    }

    // backpressure verify (normally already satisfied -> zero added latency)
    if (bp) {
      const int need = t - 2;
      int sp = 0;
      while (!__all(bpf >= need)) {
        if (++sp > SPIN_LIM) break;
        __builtin_amdgcn_s_sleep(8);
        bpf = (int)__hip_atomic_load(flags + lane, __ATOMIC_RELAXED,
                                     __HIP_MEMORY_SCOPE_AGENT);
      }
    }

    // re-poison the slot that will carry h[t+2] (now holds h[t-6]/h[t-2]).
    // Pre-barrier: mid-barrier vmcnt drain orders it before this publish.
    if ((eu & 1) == 0) {
      unsigned char* pb = (L == 0) ? h0buf + (size_t)((t + 2) & 7) * 32768
                                   : h1buf + (size_t)((t + 2) & 3) * 32768;
      __hip_atomic_store(reinterpret_cast<unsigned*>(pb + pub_off), POISON,
                         __ATOMIC_RELAXED, __HIP_MEMORY_SCOPE_AGENT);
    }

    // MFMA: 16 ktiles x 2 ntiles, fp32 accum
    f32x4 acc0 = {0.f, 0.f, 0.f, 0.f}, acc1 = {0.f, 0.f, 0.f, 0.f};
#pragma unroll
    for (int kt2 = 0; kt2 < 16; ++kt2) {
      bf16x8 a = __builtin_bit_cast(bf16x8, af[kt2]);
      acc0 = __builtin_amdgcn_mfma_f32_16x16x32_bf16(
          a, __builtin_bit_cast(bf16x8, Bf[0][kt2]), acc0, 0, 0, 0);
      acc1 = __builtin_amdgcn_mfma_f32_16x16x32_bf16(
          a, __builtin_bit_cast(bf16x8, Bf[1][kt2]), acc1, 0, 0, 0);
    }

    // z partials -> LDS (C layout: col = lane&15, row = (lane>>4)*4 + reg)
    {
      int r0 = m * 16 + (lane >> 4) * 4;
      int cc = lane & 15;
      float* zp = zbuf + kh * (32 * 33);
#pragma unroll
      for (int r = 0; r < 4; ++r) {
        zp[(r0 + r) * 33 + cc]      = acc0[r];
        zp[(r0 + r) * 33 + 16 + cc] = acc1[r];
      }
    }
    __syncthreads();   // mid-barrier: z visible; drains poison (+ old stores)

    // layer-1 progress: all of this step's h reads are complete here
    if (L == 1 && tid == 0)
      __hip_atomic_store(flags + slice, t + 1, __ATOMIC_RELAXED,
                         __HIP_MEMORY_SCOPE_AGENT);

    // epilogue: thread (eb, eu) owns one hidden unit; stores held in regs
    float hv;
    unsigned packed;
    {
      float zi = zbuf[eb * 33 + eu]      + zbuf[1056 + eb * 33 + eu]      + blds[eu];
      float zf = zbuf[eb * 33 + 8 + eu]  + zbuf[1056 + eb * 33 + 8 + eu]  + blds[8 + eu];
      float zg = zbuf[eb * 33 + 16 + eu] + zbuf[1056 + eb * 33 + 16 + eu] + blds[16 + eu];
      float zo = zbuf[eb * 33 + 24 + eu] + zbuf[1056 + eb * 33 + 24 + eu] + blds[24 + eu];
      float ig = 1.f / (1.f + __expf(-zi));
      float fg = 1.f / (1.f + __expf(-zf));
      float e2 = __expf(-2.f * zg);
      float gg = (1.f - e2) / (1.f + e2);
      float og = 1.f / (1.f + __expf(-zo));
      creg = fg * creg + ig * gg;
      float ec = __expf(-2.f * creg);
      float th = (1.f - ec) / (1.f + ec);
      hv = og * th;
      unsigned hu = f2bf(hv);
      unsigned hi = (unsigned)__shfl_down((int)hu, 1);
      packed = (hu & 0xffffu) | (hi << 16);
    }
    __syncthreads();   // zbuf safe to overwrite next iteration

    // publish AFTER the barrier: fire-and-forget relaxed stores whose flight
    // overlaps the next step's poll (no release fence, no vmcnt(0) drain here)
    if (L == 1) out0[((size_t)eb * NS + t) * ND + u0 + eu] = hv;
    if ((eu & 1) == 0) {
      unsigned char* dst = ((L == 0) ? h0buf + (size_t)(t & 7) * 32768
                                     : h1buf + (size_t)(t & 3) * 32768) + pub_off;
      __hip_atomic_store(reinterpret_cast<unsigned*>(dst), packed,
                         __ATOMIC_RELAXED, __HIP_MEMORY_SCOPE_AGENT);
    }
  }
}

extern "C" void kernel_launch(void* const* d_in, const int* in_sizes, int n_in,
                              void* d_out, int out_size, void* d_ws, size_t ws_size,
                              hipStream_t stream) {
  const int*   src = (const int*)d_in[0];
  // d_in[1] = source_len (unused by the reference computation)
  const float* emb = (const float*)d_in[2];
  const float* Wk  = (const float*)d_in[3];
  const float* Wr  = (const float*)d_in[4];
  const float* bg  = (const float*)d_in[5];

  float* out0 = (float*)d_out;                        // LSTM output [32,512,512]
  float* out1 = out0 + (size_t)NB * NS * ND;          // source_emb [32,512,512]
  unsigned char* ws = (unsigned char*)d_ws;

  // output 1: embedding gather (also the fp32 x source for layer 0)
  gather_f32<<<8192, 256, 0, stream>>>(src, emb, out1);

  // control-block init every call: flags -> 0, all h slots -> poison (0xFF)
  hipMemsetAsync(ws + FLAGS_OFF, 0, H0_OFF, stream);
  hipMemsetAsync(ws + H0_OFF, 0xFF, CTRL_BYTES - H0_OFF, stream);

  lstm_persist<<<128, 256, 0, stream>>>(Wk, Wr, bg, out1, ws, out0);
}

// Round 2
// 3632.703 us; speedup vs baseline: 1.0199x; 1.0199x over previous
//
#include <hip/hip_runtime.h>
#include <hip/hip_bf16.h>
#include <cstddef>
#include <cstdint>

// Problem constants
#define NB 32          // batch
#define NS 512         // seq len
#define ND 512         // d_model == hid
#define NG 2048        // 4*hid gate cols per layer

// ws layout (bytes).  Poison-mailbox, FULL-DEPTH h0 edition.
//   h1 : 4 slots x 32768 B frag-order bf16, slot = t & 3        (layer-1 self)
//   h0 : 512 slots x 32768 B, slot = t                          (layer-0 out)
// Everything is poisoned ONCE by a single hipMemsetAsync(0xFF) before launch.
// h0 slots are write-once: no re-poisoning, no backpressure flags, no
// overwrite hazards anywhere on layer-0's critical cycle.  Producers publish
// packed 32-bit words (2 x bf16; |h|<1 can never encode 0xFFFF).  Consumers
// poll their exact MFMA A-fragment words until != 0xFFFFFFFF -- the last
// poll round's loads ARE the fragments (single roundtrip).
// h1 (4-deep) is re-poisoned by layer-1 blocks only: at step t, slot (t+2)&3
// (holds h1[t-2]).  Safe: the poisoner's poll of h1[t-1] already observed
// every peer's publish of t-1, which happens after their step-(t-1) reads of
// h1[t-2] returned; the poison store is control-dependent on that poll.
#define H1_OFF   0
#define H0_OFF   (4 * 32768)                    // 131072
#define WS_NEED  (H0_OFF + 512 * 32768)         // 16,908,288 B (proven fits)

#define POISON   0xFFFFFFFFu
#define SPIN_LIM 16384                          // fail-safe: never hang

typedef __attribute__((ext_vector_type(8))) short short8;
typedef __attribute__((ext_vector_type(8))) __bf16 bf16x8;
typedef __attribute__((ext_vector_type(4))) float f32x4;

static __device__ __forceinline__ unsigned short f2bf(float f) {
  __hip_bfloat16 h = __float2bfloat16(f);
  return __builtin_bit_cast(unsigned short, h);
}

static __device__ __forceinline__ short8 pack8(float4 a, float4 b) {
  short8 r;
  r[0] = (short)f2bf(a.x); r[1] = (short)f2bf(a.y);
  r[2] = (short)f2bf(a.z); r[3] = (short)f2bf(a.w);
  r[4] = (short)f2bf(b.x); r[5] = (short)f2bf(b.y);
  r[6] = (short)f2bf(b.z); r[7] = (short)f2bf(b.w);
  return r;
}

static __device__ __forceinline__ unsigned long long aload64(const unsigned char* p) {
  return __hip_atomic_load(reinterpret_cast<const unsigned long long*>(p),
                           __ATOMIC_RELAXED, __HIP_MEMORY_SCOPE_AGENT);
}

// ---------------- Kernel 1: fp32 embedding gather (output 1 + LSTM x) -------
__global__ __launch_bounds__(256) void gather_f32(const int* __restrict__ src,
                                                  const float* __restrict__ emb,
                                                  float* __restrict__ out1) {
  int tid = blockIdx.x * 256 + threadIdx.x;   // 0 .. 2097151 (float4 granules)
  int bt = tid >> 7;                          // b*512 + t
  int k4 = (tid & 127) << 2;
  int s  = src[bt];
  float4 v = *reinterpret_cast<const float4*>(emb + (size_t)s * ND + k4);
  *reinterpret_cast<float4*>(out1 + (size_t)bt * ND + k4) = v;
}

// ---------------- Kernel 2: persistent 2-layer LSTM ----------------
// grid = 128 blocks: L = bid>>6, slice = bid&63 (8 hidden units / 32 gate cols)
__global__ __launch_bounds__(256, 1) void lstm_persist(
    const float* __restrict__ Wk, const float* __restrict__ Wr,
    const float* __restrict__ bias_g,
    const float* __restrict__ x_f32,          // gathered fp32 emb (out1)
    unsigned char* ws, float* __restrict__ out0) {

  __shared__ __attribute__((aligned(16))) char smem[66048];

  const int tid   = threadIdx.x;
  const int bid   = blockIdx.x;
  const int L     = bid >> 6;
  const int slice = bid & 63;
  const int u0    = slice * 8;
  const int lane  = tid & 63;
  const int wv    = tid >> 6;
  const int m     = wv & 1;    // batch mtile (16 rows)
  const int kh    = wv >> 1;   // K half (16 ktiles of 32)

  const float* WkL = Wk + (size_t)L * 512 * NG;
  const float* WrL = Wr + (size_t)L * 512 * NG;

  // ---- phase 1: stage transposed weight slice into LDS: WT[32 cols][1032 k]
  short* WT = reinterpret_cast<short*>(smem);
  for (int idx = tid; idx < 1024 * 32; idx += 256) {
    int k = idx >> 5, c = idx & 31;
    int gc = (c >> 3) * 512 + u0 + (c & 7);        // cols ordered [i8|f8|g8|o8]
    float v = (k < 512) ? WkL[(size_t)k * NG + gc]
                        : WrL[(size_t)(k - 512) * NG + gc];
    WT[c * 1032 + k] = (short)f2bf(v);
  }
  __syncthreads();

  // ---- preload static B fragments into VGPRs (32 frags = 128 VGPRs/thread)
  short8 Bf[2][16];
  {
    int colr = lane & 15;
    int q    = lane >> 4;
#pragma unroll
    for (int n = 0; n < 2; ++n)
#pragma unroll
      for (int kt2 = 0; kt2 < 16; ++kt2) {
        int k = (kh * 16 + kt2) * 32 + q * 8;
        Bf[n][kt2] = *reinterpret_cast<const short8*>(WT + (n * 16 + colr) * 1032 + k);
      }
  }
  __syncthreads();

  // ---- LDS reused, parity-double-buffered z partials:
  //   zbuf[par][2 kh][32 b][33] f32  (par = t&1)  +  bias[32]
  float* zb   = reinterpret_cast<float*>(smem);   // 2 x 2112 floats
  float* blds = zb + 2 * 2112;                    // 32 floats
  if (tid < 32) {
    int gc = (tid >> 3) * 512 + u0 + (tid & 7);
    blds[tid] = bias_g[L * NG + gc];
  }
  __syncthreads();

  unsigned char* h1buf = ws + H1_OFF;
  unsigned char* h0buf = ws + H0_OFF;

  // epilogue thread mapping: (b,u) and publish offset into frag-order h buffer
  const int eb = tid >> 3, eu = tid & 7;
  const int pub_off = ((u0 >> 5) * 2 + (eb >> 4)) * 1024 +
                      ((u0 & 31) >> 3) * 256 + (eb & 15) * 16 + eu * 2;

  float creg = 0.f;

  for (int t = 0; t < NS; ++t) {
    short8 af[16];

    if (L == 0 && kh == 0) {
      // x side: no dependency; fully overlapped with the other waves' polls
      int bb = m * 16 + (lane & 15);
      const float* xr = x_f32 + ((size_t)bb * NS + t) * ND + (lane >> 4) * 8;
#pragma unroll
      for (int kt2 = 0; kt2 < 16; ++kt2) {
        float4 v0 = *reinterpret_cast<const float4*>(xr + kt2 * 32);
        float4 v1 = *reinterpret_cast<const float4*>(xr + kt2 * 32 + 4);
        af[kt2] = pack8(v0, v1);
      }
    } else if (t == 0 && kh == 1) {
      // self-layer h[-1] == 0 (slots start poisoned; skip them entirely)
      const short8 zz = {0, 0, 0, 0, 0, 0, 0, 0};
#pragma unroll
      for (int kt2 = 0; kt2 < 16; ++kt2) af[kt2] = zz;
    } else {
      const unsigned char* hb;
      if (L == 0)       hb = h0buf + (size_t)(t - 1) * 32768;        // h0[t-1]
      else if (kh == 0) hb = h0buf + (size_t)t * 32768;              // h0[t]
      else              hb = h1buf + (size_t)((t - 1) & 3) * 32768;  // h1[t-1]
      const unsigned char* ha = hb + (size_t)m * 1024 + lane * 16;
      // data poll: 32x8B agent-scope loads into af, then poison check; the
      // successful round's loads ARE the MFMA A-fragments (one roundtrip).
      int spin = 0;
      for (;;) {
#pragma unroll
        for (int kt2 = 0; kt2 < 16; ++kt2) {
          unsigned long long* ap = reinterpret_cast<unsigned long long*>(&af[kt2]);
          ap[0] = aload64(ha + (size_t)kt2 * 2048);
          ap[1] = aload64(ha + (size_t)kt2 * 2048 + 8);
        }
        unsigned ok = 1u;
#pragma unroll
        for (int kt2 = 0; kt2 < 16; ++kt2) {
          const unsigned long long* ap =
              reinterpret_cast<const unsigned long long*>(&af[kt2]);
          unsigned w0 = (unsigned)ap[0], w1 = (unsigned)(ap[0] >> 32);
          unsigned w2 = (unsigned)ap[1], w3 = (unsigned)(ap[1] >> 32);
          ok &= (unsigned)(w0 != POISON) & (unsigned)(w1 != POISON) &
                (unsigned)(w2 != POISON) & (unsigned)(w3 != POISON);
        }
        if (ok || ++spin > SPIN_LIM) break;   // bail-out: no hang, ever
        __builtin_amdgcn_s_sleep(1);
      }
    }

    // h1 re-poison (layer 1 only): slot (t+2)&3 currently holds h1[t-2];
    // control-dependent on this step's poll (all peers' t-1 reads finished).
    // Ordered before this step's publish by the barrier's vmcnt(0) drain.
    if (L == 1 && (eu & 1) == 0) {
      unsigned char* pb = h1buf + (size_t)((t + 2) & 3) * 32768;
      __hip_atomic_store(reinterpret_cast<unsigned*>(pb + pub_off), POISON,
                         __ATOMIC_RELAXED, __HIP_MEMORY_SCOPE_AGENT);
    }

    // MFMA: 16 ktiles x 2 ntiles, fp32 accum
    f32x4 acc0 = {0.f, 0.f, 0.f, 0.f}, acc1 = {0.f, 0.f, 0.f, 0.f};
#pragma unroll
    for (int kt2 = 0; kt2 < 16; ++kt2) {
      bf16x8 a = __builtin_bit_cast(bf16x8, af[kt2]);
      acc0 = __builtin_amdgcn_mfma_f32_16x16x32_bf16(
          a, __builtin_bit_cast(bf16x8, Bf[0][kt2]), acc0, 0, 0, 0);
      acc1 = __builtin_amdgcn_mfma_f32_16x16x32_bf16(
          a, __builtin_bit_cast(bf16x8, Bf[1][kt2]), acc1, 0, 0, 0);
    }

    // z partials -> LDS parity buffer (C layout: col=lane&15, row=(lane>>4)*4+r)
    {
      int r0 = m * 16 + (lane >> 4) * 4;
      int cc = lane & 15;
      float* zp = zb + (t & 1) * 2112 + kh * (32 * 33);
#pragma unroll
      for (int r = 0; r < 4; ++r) {
        zp[(r0 + r) * 33 + cc]      = acc0[r];
        zp[(r0 + r) * 33 + 16 + cc] = acc1[r];
      }
    }
    __syncthreads();   // the ONLY barrier per step: z visible, poisons drained

    // epilogue: thread (eb, eu) owns one hidden unit
    {
      const float* zq = zb + (t & 1) * 2112;
      float zi = zq[eb * 33 + eu]      + zq[1056 + eb * 33 + eu]      + blds[eu];
      float zf = zq[eb * 33 + 8 + eu]  + zq[1056 + eb * 33 + 8 + eu]  + blds[8 + eu];
      float zg = zq[eb * 33 + 16 + eu] + zq[1056 + eb * 33 + 16 + eu] + blds[16 + eu];
      float zo = zq[eb * 33 + 24 + eu] + zq[1056 + eb * 33 + 24 + eu] + blds[24 + eu];
      float ig = 1.f / (1.f + __expf(-zi));
      float fg = 1.f / (1.f + __expf(-zf));
      float e2 = __expf(-2.f * zg);
      float gg = (1.f - e2) / (1.f + e2);
      float og = 1.f / (1.f + __expf(-zo));
      creg = fg * creg + ig * gg;
      float ec = __expf(-2.f * creg);
      float th = (1.f - ec) / (1.f + ec);
      float hv = og * th;

      unsigned hu = f2bf(hv);
      unsigned hi = (unsigned)__shfl_down((int)hu, 1);

      // publish FIRST (critical path): fire-and-forget relaxed stores; their
      // ack drains at the NEXT step's barrier, overlapped with the next poll.
      if ((eu & 1) == 0) {
        unsigned packed = (hu & 0xffffu) | (hi << 16);
        unsigned char* dst = (L == 0)
            ? h0buf + (size_t)t * 32768 + pub_off
            : h1buf + (size_t)(t & 3) * 32768 + pub_off;
        __hip_atomic_store(reinterpret_cast<unsigned*>(dst), packed,
                           __ATOMIC_RELAXED, __HIP_MEMORY_SCOPE_AGENT);
      }
      if (L == 1) out0[((size_t)eb * NS + t) * ND + u0 + eu] = hv;
    }
    // no second barrier: next iteration writes the other zbuf parity
  }
}

extern "C" void kernel_launch(void* const* d_in, const int* in_sizes, int n_in,
                              void* d_out, int out_size, void* d_ws, size_t ws_size,
                              hipStream_t stream) {
  const int*   src = (const int*)d_in[0];
  // d_in[1] = source_len (unused by the reference computation)
  const float* emb = (const float*)d_in[2];
  const float* Wk  = (const float*)d_in[3];
  const float* Wr  = (const float*)d_in[4];
  const float* bg  = (const float*)d_in[5];

  float* out0 = (float*)d_out;                        // LSTM output [32,512,512]
  float* out1 = out0 + (size_t)NB * NS * ND;          // source_emb [32,512,512]
  unsigned char* ws = (unsigned char*)d_ws;

  // output 1: embedding gather (also the fp32 x source for layer 0)
  gather_f32<<<8192, 256, 0, stream>>>(src, emb, out1);

  // one-shot poison of ALL h slots (h1 4-deep + h0 full-depth 512)
  hipMemsetAsync(ws, 0xFF, WS_NEED, stream);

  lstm_persist<<<128, 256, 0, stream>>>(Wk, Wr, bg, out1, ws, out0);
}

// Round 4
// 2830.393 us; speedup vs baseline: 1.3090x; 1.2835x over previous
//
#include <hip/hip_runtime.h>
#include <hip/hip_bf16.h>
#include <cstddef>
#include <cstdint>

// Problem constants
#define NB 32          // batch
#define NS 512         // seq len
#define ND 512         // d_model == hid
#define NG 2048        // 4*hid gate cols per layer

// ws layout. Poison-mailbox + dedicated-writer-wave (R4: proven atomic polls).
//   flags[64] : layer-1 progress (backpressure, checked by L0 x-wave wv0)
//   h1 : 16 slots x 32768 B frag-order bf16, slot = t & 15
//   h0 : 32 slots x 32768 B,                 slot = t & 31
// One 32KB slot, element (b,k):
//   (b>>4)*16384 + (k>>5)*1024 + ((k>>3)&3)*256 + (b&15)*16 + (k&7)*2
// so a polling wave (batch-half m) reads a contiguous 16KB region.
// Protocol: all h publishes/polls are relaxed agent-scope atomics (the exact
// semantics that passed R0-R2 -- device-coherent, no stale-L2 hazard).
// Legit |h|<1 never encodes bf16 0xFFFF, so word 0xFFFFFFFF is impossible;
// publish granularity is 4B and the check granularity is 4B -> no torn reads.
// Structural change under test: wave 4 owns ALL global stores; waves 0-3
// never store, so their poll waits never drain store acks. Barriers are raw
// lgkmcnt(0)+s_barrier (no vmcnt drain anywhere in the loop). Writer caps
// outstanding stores with vmcnt(8) (~1.5 steps in flight).
// Slot-reuse safety: L0/L1 intra-layer skew <=~2 steps (full-vector poll is
// a rendezvous); L0->L1 skew bounded by flags-backpressure (L1 >= t-13 worst
// case); L0 writer at iter t poisons the slot holding h0[t-17] < t-13. ✓
#define FLAGS_OFF 0
#define H1_OFF    4096
#define H1_SLOTS  16
#define H0_OFF    (H1_OFF + H1_SLOTS * 32768)
#define H0_SLOTS  32
#define WS_NEED   (H0_OFF + H0_SLOTS * 32768)   // ~1.6 MB

#define POISON   0xFFFFFFFFu
#define SPIN_LIM (1 << 17)

typedef __attribute__((ext_vector_type(8))) short short8;
typedef __attribute__((ext_vector_type(8))) __bf16 bf16x8;
typedef __attribute__((ext_vector_type(4))) float f32x4;

static __device__ __forceinline__ unsigned short f2bf(float f) {
  __hip_bfloat16 h = __float2bfloat16(f);
  return __builtin_bit_cast(unsigned short, h);
}

static __device__ __forceinline__ short8 pack8(float4 a, float4 b) {
  short8 r;
  r[0] = (short)f2bf(a.x); r[1] = (short)f2bf(a.y);
  r[2] = (short)f2bf(a.z); r[3] = (short)f2bf(a.w);
  r[4] = (short)f2bf(b.x); r[5] = (short)f2bf(b.y);
  r[6] = (short)f2bf(b.z); r[7] = (short)f2bf(b.w);
  return r;
}

static __device__ __forceinline__ unsigned long long aload64(const unsigned char* p) {
  return __hip_atomic_load(reinterpret_cast<const unsigned long long*>(p),
                           __ATOMIC_RELAXED, __HIP_MEMORY_SCOPE_AGENT);
}

// raw barrier: LDS-visibility only, NO vmcnt drain (stores stay in flight)
#define BARRIER_LGKM() asm volatile("s_waitcnt lgkmcnt(0)\n\ts_barrier" ::: "memory")

// ---------------- Kernel 1: fp32 embedding gather (output 1 + LSTM x) -------
__global__ __launch_bounds__(256) void gather_f32(const int* __restrict__ src,
                                                  const float* __restrict__ emb,
                                                  float* __restrict__ out1) {
  int tid = blockIdx.x * 256 + threadIdx.x;   // 0 .. 2097151 (float4 granules)
  int bt = tid >> 7;                          // b*512 + t
  int k4 = (tid & 127) << 2;
  int s  = src[bt];
  float4 v = *reinterpret_cast<const float4*>(emb + (size_t)s * ND + k4);
  *reinterpret_cast<float4*>(out1 + (size_t)bt * ND + k4) = v;
}

// ---------------- Kernel 2: persistent 2-layer LSTM ----------------
// grid = 128 blocks of 320 threads (5 waves), 1 block/CU (co-residency safe).
// L = bid>>6, slice = bid&63 (8 hidden units / 32 gate cols per block).
// waves 0..3 (m = wv&1 batch half, kh = wv>>1 K half): compute; NEVER store.
// wave 4: writer — epilogue for step t-1, all publishes/poisons/out0/flags.
__global__ __launch_bounds__(320, 1) void lstm_persist(
    const float* __restrict__ Wk, const float* __restrict__ Wr,
    const float* __restrict__ bias_g,
    const float* __restrict__ x_f32,          // gathered fp32 emb (out1)
    unsigned char* ws, float* __restrict__ out0) {

  __shared__ __attribute__((aligned(16))) char smem[66048];

  const int tid   = threadIdx.x;
  const int bid   = blockIdx.x;
  const int L     = bid >> 6;
  const int slice = bid & 63;
  const int u0    = slice * 8;
  const int lane  = tid & 63;
  const int wv    = tid >> 6;                 // 0..4
  const int m     = wv & 1;                   // batch mtile (16 rows)
  const int kh    = wv >> 1;                  // K half (for compute waves)

  const float* WkL = Wk + (size_t)L * 512 * NG;
  const float* WrL = Wr + (size_t)L * 512 * NG;

  // ---- phase 1: stage transposed weight slice into LDS: WT[32 cols][1032 k]
  short* WT = reinterpret_cast<short*>(smem);
  for (int idx = tid; idx < 1024 * 32; idx += 320) {
    int k = idx >> 5, c = idx & 31;
    int gc = (c >> 3) * 512 + u0 + (c & 7);        // cols ordered [i8|f8|g8|o8]
    float v = (k < 512) ? WkL[(size_t)k * NG + gc]
                        : WrL[(size_t)(k - 512) * NG + gc];
    WT[c * 1032 + k] = (short)f2bf(v);
  }
  __syncthreads();

  // ---- preload static B fragments into VGPRs (compute waves only)
  short8 Bf[2][16];
  if (wv < 4) {
    int colr = lane & 15;
    int q    = lane >> 4;
#pragma unroll
    for (int n = 0; n < 2; ++n)
#pragma unroll
      for (int kt2 = 0; kt2 < 16; ++kt2) {
        int k = (kh * 16 + kt2) * 32 + q * 8;
        Bf[n][kt2] = *reinterpret_cast<const short8*>(WT + (n * 16 + colr) * 1032 + k);
      }
  }
  __syncthreads();

  // ---- LDS reused: parity-double-buffered z partials + bias
  float* zb   = reinterpret_cast<float*>(smem);   // 2 x 2112 floats
  float* blds = zb + 2 * 2112;                    // 32 floats
  if (tid < 32) {
    int gc = (tid >> 3) * 512 + u0 + (tid & 7);
    blds[tid] = bias_g[L * NG + gc];
  }
  __syncthreads();

  int* flags = reinterpret_cast<int*>(ws + FLAGS_OFF);
  unsigned char* h1buf = ws + H1_OFF;
  unsigned char* h0buf = ws + H0_OFF;

  // writer-wave per-lane mapping: 4 hidden units per lane
  const int eb   = lane >> 1;                // batch row 0..31
  const int eu_b = (lane & 1) * 4;           // eu base: 0 or 4
  const size_t pub_base = (size_t)(eb >> 4) * 16384 + (size_t)(u0 >> 5) * 1024 +
                          (size_t)((u0 >> 3) & 3) * 256 + (size_t)(eb & 15) * 16 +
                          (size_t)eu_b * 2;
  float creg0 = 0.f, creg1 = 0.f, creg2 = 0.f, creg3 = 0.f;

  for (int t = 0; t <= NS; ++t) {
    if (wv < 4 && t < NS) {
      short8 af[16];

      if (L == 0 && kh == 0) {
        // ---- x waves: pure loads. wv==0 also runs the backpressure check.
        int bpf = 0;
        const bool bp = (wv == 0) && ((t & 3) == 0) && (t >= 16);
        if (bp) bpf = (int)__hip_atomic_load(flags + lane, __ATOMIC_RELAXED,
                                             __HIP_MEMORY_SCOPE_AGENT);
        int bb = m * 16 + (lane & 15);
        const float* xr = x_f32 + ((size_t)bb * NS + t) * ND + (lane >> 4) * 8;
#pragma unroll
        for (int kt2 = 0; kt2 < 16; ++kt2) {
          float4 v0 = *reinterpret_cast<const float4*>(xr + kt2 * 32);
          float4 v1 = *reinterpret_cast<const float4*>(xr + kt2 * 32 + 4);
          af[kt2] = pack8(v0, v1);
        }
        if (bp) {
          int sp = 0;
          while (!__all(bpf >= t - 10)) {          // L1 epilogue past t-10?
            if (++sp > SPIN_LIM) break;            // fail-safe, never hang
            __builtin_amdgcn_s_sleep(8);
            bpf = (int)__hip_atomic_load(flags + lane, __ATOMIC_RELAXED,
                                         __HIP_MEMORY_SCOPE_AGENT);
          }
        }
      } else if (t == 0 && kh == 1) {
        // self-layer h[-1] == 0 (slots start poisoned; never read them)
        const short8 zz = {0, 0, 0, 0, 0, 0, 0, 0};
#pragma unroll
        for (int kt2 = 0; kt2 < 16; ++kt2) af[kt2] = zz;
      } else {
        // ---- data poll: relaxed agent atomic loads (proven coherent).
        // The successful round's loads ARE the MFMA A-fragments.
        const unsigned char* hb;
        if (L == 0)       hb = h0buf + (size_t)((t - 1) & 31) * 32768;  // h0[t-1]
        else if (kh == 0) hb = h0buf + (size_t)(t & 31) * 32768;        // h0[t]
        else              hb = h1buf + (size_t)((t - 1) & 15) * 32768;  // h1[t-1]
        const unsigned char* ha = hb + (size_t)m * 16384 +
                                  (size_t)(lane >> 4) * 256 + (size_t)(lane & 15) * 16;
        int spin = 0;
        for (;;) {
#pragma unroll
          for (int i = 0; i < 4; ++i) {
#pragma unroll
            for (int j = 0; j < 4; ++j) {
              unsigned long long* ap =
                  reinterpret_cast<unsigned long long*>(&af[i * 4 + j]);
              const unsigned char* p = ha + (size_t)i * 4096 + (size_t)j * 1024;
              ap[0] = aload64(p);
              ap[1] = aload64(p + 8);
            }
          }
          unsigned ok = 1u;
#pragma unroll
          for (int i = 0; i < 16; ++i) {
            const unsigned long long* ap =
                reinterpret_cast<const unsigned long long*>(&af[i]);
            unsigned w0 = (unsigned)ap[0], w1 = (unsigned)(ap[0] >> 32);
            unsigned w2 = (unsigned)ap[1], w3 = (unsigned)(ap[1] >> 32);
            ok &= (unsigned)(w0 != POISON) & (unsigned)(w1 != POISON) &
                  (unsigned)(w2 != POISON) & (unsigned)(w3 != POISON);
          }
          if (ok) break;
          if (++spin > SPIN_LIM) break;            // fail-safe: fail loudly
          if (spin > 8) __builtin_amdgcn_s_sleep(1);
        }
      }

      // ---- MFMA: 16 ktiles x 2 ntiles, fp32 accum
      f32x4 acc0 = {0.f, 0.f, 0.f, 0.f}, acc1 = {0.f, 0.f, 0.f, 0.f};
#pragma unroll
      for (int kt2 = 0; kt2 < 16; ++kt2) {
        bf16x8 a = __builtin_bit_cast(bf16x8, af[kt2]);
        acc0 = __builtin_amdgcn_mfma_f32_16x16x32_bf16(
            a, __builtin_bit_cast(bf16x8, Bf[0][kt2]), acc0, 0, 0, 0);
        acc1 = __builtin_amdgcn_mfma_f32_16x16x32_bf16(
            a, __builtin_bit_cast(bf16x8, Bf[1][kt2]), acc1, 0, 0, 0);
      }

      // ---- z partials -> LDS parity buffer
      {
        int r0 = m * 16 + (lane >> 4) * 4;
        int cc = lane & 15;
        float* zp = zb + (t & 1) * 2112 + kh * (32 * 33);
#pragma unroll
        for (int r = 0; r < 4; ++r) {
          zp[(r0 + r) * 33 + cc]      = acc0[r];
          zp[(r0 + r) * 33 + 16 + cc] = acc1[r];
        }
      }
    } else if (wv == 4 && t > 0) {
      // ---- writer wave: finish step tp = t-1 (its z was written last iter)
      const int tp = t - 1;
      const float* zq = zb + (tp & 1) * 2112;
      float hv0, hv1, hv2, hv3;
      {
        float hv[4];
#pragma unroll
        for (int j = 0; j < 4; ++j) {
          int eu = eu_b + j;
          float zi = zq[eb * 33 + eu]      + zq[1056 + eb * 33 + eu]      + blds[eu];
          float zf = zq[eb * 33 + 8 + eu]  + zq[1056 + eb * 33 + 8 + eu]  + blds[8 + eu];
          float zg = zq[eb * 33 + 16 + eu] + zq[1056 + eb * 33 + 16 + eu] + blds[16 + eu];
          float zo = zq[eb * 33 + 24 + eu] + zq[1056 + eb * 33 + 24 + eu] + blds[24 + eu];
          float ig = 1.f / (1.f + __expf(-zi));
          float fg = 1.f / (1.f + __expf(-zf));
          float e2 = __expf(-2.f * zg);
          float gg = (1.f - e2) / (1.f + e2);
          float og = 1.f / (1.f + __expf(-zo));
          float c_old = (j == 0) ? creg0 : (j == 1) ? creg1 : (j == 2) ? creg2 : creg3;
          float c_new = fg * c_old + ig * gg;
          if (j == 0) creg0 = c_new; else if (j == 1) creg1 = c_new;
          else if (j == 2) creg2 = c_new; else creg3 = c_new;
          float ec = __expf(-2.f * c_new);
          hv[j] = og * ((1.f - ec) / (1.f + ec));
        }
        hv0 = hv[0]; hv1 = hv[1]; hv2 = hv[2]; hv3 = hv[3];
      }

      // publish h[tp]: two packed 4B relaxed agent stores
      unsigned p0 = ((unsigned)f2bf(hv0) & 0xffffu) | ((unsigned)f2bf(hv1) << 16);
      unsigned p1 = ((unsigned)f2bf(hv2) & 0xffffu) | ((unsigned)f2bf(hv3) << 16);
      unsigned char* dst = (L == 0)
          ? h0buf + (size_t)(tp & 31) * 32768 + pub_base
          : h1buf + (size_t)(tp & 15) * 32768 + pub_base;
      __hip_atomic_store(reinterpret_cast<unsigned*>(dst), p0,
                         __ATOMIC_RELAXED, __HIP_MEMORY_SCOPE_AGENT);
      __hip_atomic_store(reinterpret_cast<unsigned*>(dst + 4), p1,
                         __ATOMIC_RELAXED, __HIP_MEMORY_SCOPE_AGENT);

      // re-poison the slot that will carry h[tp+16]/h[tp+8] (holds
      // h[tp-16]/h[tp-8]; all readers provably done per skew bounds above)
      unsigned char* pb = (L == 0)
          ? h0buf + (size_t)((tp + 16) & 31) * 32768 + pub_base
          : h1buf + (size_t)((tp + 8) & 15) * 32768 + pub_base;
      __hip_atomic_store(reinterpret_cast<unsigned*>(pb), POISON,
                         __ATOMIC_RELAXED, __HIP_MEMORY_SCOPE_AGENT);
      __hip_atomic_store(reinterpret_cast<unsigned*>(pb + 4), POISON,
                         __ATOMIC_RELAXED, __HIP_MEMORY_SCOPE_AGENT);

      if (L == 1) {
        // final output: 4 consecutive units -> one float4 store
        float4 o4 = make_float4(hv0, hv1, hv2, hv3);
        *reinterpret_cast<float4*>(
            out0 + ((size_t)eb * NS + tp) * ND + u0 + eu_b) = o4;
        // progress flag for L0 backpressure
        if (lane == 0)
          __hip_atomic_store(flags + slice, tp, __ATOMIC_RELAXED,
                             __HIP_MEMORY_SCOPE_AGENT);
      }
      // cap outstanding stores (~<=1.5 steps in flight); never a full drain
      asm volatile("s_waitcnt vmcnt(8)" ::: "memory");
    }

    BARRIER_LGKM();   // one barrier/iter: z[t] visible to wave4 at iter t+1
  }
}

extern "C" void kernel_launch(void* const* d_in, const int* in_sizes, int n_in,
                              void* d_out, int out_size, void* d_ws, size_t ws_size,
                              hipStream_t stream) {
  const int*   src = (const int*)d_in[0];
  // d_in[1] = source_len (unused by the reference computation)
  const float* emb = (const float*)d_in[2];
  const float* Wk  = (const float*)d_in[3];
  const float* Wr  = (const float*)d_in[4];
  const float* bg  = (const float*)d_in[5];

  float* out0 = (float*)d_out;                        // LSTM output [32,512,512]
  float* out1 = out0 + (size_t)NB * NS * ND;          // source_emb [32,512,512]
  unsigned char* ws = (unsigned char*)d_ws;

  // output 1: embedding gather (also the fp32 x source for layer 0)
  gather_f32<<<8192, 256, 0, stream>>>(src, emb, out1);

  // per-call init: flags -> 0, all h slots -> poison (0xFF)
  hipMemsetAsync(ws + FLAGS_OFF, 0, H1_OFF, stream);
  hipMemsetAsync(ws + H1_OFF, 0xFF, WS_NEED - H1_OFF, stream);

  lstm_persist<<<128, 320, 0, stream>>>(Wk, Wr, bg, out1, ws, out0);
}